// Round 1
// baseline (1383.053 us; speedup 1.0000x reference)
//
#include <hip/hip_runtime.h>
#include <stdint.h>

#define H_ 8
#define D_ 64
#define EMBD 512
#define HD_ 512
#define B_ 4
#define S_ 1024
#define XL_ 1024
#define J_ 2048
#define KK_ 32
#define OUT1 (B_*S_*EMBD)   // 2097152 floats: "out"; kv memory follows

typedef __bf16 bf16x8 __attribute__((ext_vector_type(8)));
typedef float f32x4 __attribute__((ext_vector_type(4)));

__device__ __forceinline__ uint32_t pack2bf(float a, float b) {
    uint32_t ua = __builtin_bit_cast(uint32_t, a);
    uint32_t ub = __builtin_bit_cast(uint32_t, b);
    ua = (ua + 0x7FFFu + ((ua >> 16) & 1u)) >> 16;
    ub = (ub + 0x7FFFu + ((ub >> 16) & 1u)) >> 16;
    return ua | (ub << 16);
}

// ---------------------------------------------------------------------------
// GEMM: out[m,n] = sum_k A[m,k]*W[n,k] + bias[n]   (A:[4096,512], W:[512,512])
// bf16 MFMA 16x16x32. Tile 64x64, BK=64, 256 thr / 4 waves, wave w -> rows w*16..+15.
// mode 0: out[m*512+n]   (q workspace / final out)
// mode 1: out[m*1024+n]          (k -> kv memory [b,s,0,hd])
// mode 2: out[m*1024+512+n]      (v -> kv memory [b,s,1,hd])
// ---------------------------------------------------------------------------
#define GPAD 72

__global__ __launch_bounds__(256) void gemm_bt(
    const float* __restrict__ A, const float* __restrict__ W,
    const float* __restrict__ bias, float* __restrict__ out, int mode)
{
    __shared__ uint16_t a_l[64 * GPAD];
    __shared__ uint16_t w_l[64 * GPAD];
    const int t    = threadIdx.x;
    const int m0   = blockIdx.x * 64;
    const int n0   = blockIdx.y * 64;
    const int wv   = t >> 6;
    const int lane = t & 63;
    const int quad = lane >> 4;
    const int l16  = lane & 15;
    const int lrow = t >> 2;          // staging row 0..63
    const int lseg = (t & 3) * 16;    // staging col (16 floats)

    f32x4 zero = {0.f, 0.f, 0.f, 0.f};
    f32x4 acc[4] = {zero, zero, zero, zero};

    for (int k0 = 0; k0 < EMBD; k0 += 64) {
        const float* ga = A + (size_t)(m0 + lrow) * EMBD + k0 + lseg;
        const float* gw = W + (size_t)(n0 + lrow) * EMBD + k0 + lseg;
        float4 a0 = *(const float4*)(ga);
        float4 a1 = *(const float4*)(ga + 4);
        float4 a2 = *(const float4*)(ga + 8);
        float4 a3 = *(const float4*)(ga + 12);
        float4 w0 = *(const float4*)(gw);
        float4 w1 = *(const float4*)(gw + 4);
        float4 w2 = *(const float4*)(gw + 8);
        float4 w3 = *(const float4*)(gw + 12);
        uint32_t* pa = (uint32_t*)(a_l + lrow * GPAD + lseg);
        uint32_t* pw = (uint32_t*)(w_l + lrow * GPAD + lseg);
        pa[0] = pack2bf(a0.x, a0.y); pa[1] = pack2bf(a0.z, a0.w);
        pa[2] = pack2bf(a1.x, a1.y); pa[3] = pack2bf(a1.z, a1.w);
        pa[4] = pack2bf(a2.x, a2.y); pa[5] = pack2bf(a2.z, a2.w);
        pa[6] = pack2bf(a3.x, a3.y); pa[7] = pack2bf(a3.z, a3.w);
        pw[0] = pack2bf(w0.x, w0.y); pw[1] = pack2bf(w0.z, w0.w);
        pw[2] = pack2bf(w1.x, w1.y); pw[3] = pack2bf(w1.z, w1.w);
        pw[4] = pack2bf(w2.x, w2.y); pw[5] = pack2bf(w2.z, w2.w);
        pw[6] = pack2bf(w3.x, w3.y); pw[7] = pack2bf(w3.z, w3.w);
        __syncthreads();
        #pragma unroll
        for (int ks = 0; ks < 64; ks += 32) {
            bf16x8 af = *(const bf16x8*)(a_l + (wv*16 + l16) * GPAD + ks + quad*8);
            #pragma unroll
            for (int nt = 0; nt < 4; nt++) {
                bf16x8 wf = *(const bf16x8*)(w_l + (nt*16 + l16) * GPAD + ks + quad*8);
                acc[nt] = __builtin_amdgcn_mfma_f32_16x16x32_bf16(af, wf, acc[nt], 0, 0, 0);
            }
        }
        __syncthreads();
    }

    #pragma unroll
    for (int nt = 0; nt < 4; nt++) {
        const int col = n0 + nt*16 + l16;
        const float bvv = bias[col];
        #pragma unroll
        for (int r = 0; r < 4; r++) {
            const int row = m0 + wv*16 + quad*4 + r;
            const float v = acc[nt][r] + bvv;
            if (mode == 0)      out[(size_t)row * EMBD + col] = v;
            else if (mode == 1) out[(size_t)row * 1024 + col] = v;
            else                out[(size_t)row * 1024 + 512 + col] = v;
        }
    }
}

// ---------------------------------------------------------------------------
// Local XL causal attention, flash-style online softmax, fp32 vector.
// grid (S/32, H, B), block 256 = 4 waves; wave handles 8 query rows.
// QK phase: lane = j (kT transposed in LDS); PV phase: lane = d; P via LDS.
// score = (q.k + rel_pos[h,i,j]) * scale; allowed j <= i + XL.
// ---------------------------------------------------------------------------
__global__ __launch_bounds__(256) void attn_local(
    const float* __restrict__ q_ws,     // [B,S,HD]
    const float* __restrict__ xlm,      // [B,XL,2,HD]
    const float* __restrict__ kv_cur,   // [B,S,2,HD]
    const float* __restrict__ rel,      // [H,S,J]
    float* __restrict__ o_ws)           // [B,S,HD]
{
    __shared__ float qT[64][32];        // [d][row]
    __shared__ float kT[64][65];        // [d][j] (+pad)
    __shared__ float vT[64][65];        // [j][d] (+pad)
    __shared__ float pT[4][64][8];      // [wave][j][r]

    const int t    = threadIdx.x;
    const int wv   = t >> 6;
    const int lane = t & 63;
    const int b    = blockIdx.z;
    const int h    = blockIdx.y;
    const int i0   = blockIdx.x * 32;

    {   // stage q transposed: rows i0..i0+31
        const int row = t & 31;
        const int dc  = (t >> 5) * 8;
        const float* gq = q_ws + (size_t)(b*S_ + i0 + row) * HD_ + h*D_ + dc;
        float4 q0 = *(const float4*)(gq);
        float4 q1 = *(const float4*)(gq + 4);
        qT[dc+0][row] = q0.x; qT[dc+1][row] = q0.y; qT[dc+2][row] = q0.z; qT[dc+3][row] = q0.w;
        qT[dc+4][row] = q1.x; qT[dc+5][row] = q1.y; qT[dc+6][row] = q1.z; qT[dc+7][row] = q1.w;
    }

    float m_r[8], l_r[8], acc[8];
    #pragma unroll
    for (int r = 0; r < 8; r++) { m_r[r] = -1e30f; l_r[r] = 0.f; acc[r] = 0.f; }

    const int iw0    = i0 + wv*8;
    const int ntiles = ((XL_ + i0 + 31) >> 6) + 1;
    const float scale = 0.125f;
    const int sj  = t >> 2;           // staging j row 0..63
    const int sdc = (t & 3) * 16;     // staging d chunk

    for (int jt = 0; jt < ntiles; jt++) {
        const int j0 = jt << 6;
        {   // stage K/V tile (64 j x 64 d)
            const int jg = j0 + sj;
            const float* src = (jg < XL_)
                ? (xlm    + (size_t)(b*XL_ + jg) * 2 * HD_ + h*D_ + sdc)
                : (kv_cur + (size_t)(b*S_ + (jg - XL_)) * 2 * HD_ + h*D_ + sdc);
            float4 k0v = *(const float4*)(src);
            float4 k1v = *(const float4*)(src + 4);
            float4 k2v = *(const float4*)(src + 8);
            float4 k3v = *(const float4*)(src + 12);
            float4 v0v = *(const float4*)(src + HD_);
            float4 v1v = *(const float4*)(src + HD_ + 4);
            float4 v2v = *(const float4*)(src + HD_ + 8);
            float4 v3v = *(const float4*)(src + HD_ + 12);
            kT[sdc+ 0][sj] = k0v.x; kT[sdc+ 1][sj] = k0v.y; kT[sdc+ 2][sj] = k0v.z; kT[sdc+ 3][sj] = k0v.w;
            kT[sdc+ 4][sj] = k1v.x; kT[sdc+ 5][sj] = k1v.y; kT[sdc+ 6][sj] = k1v.z; kT[sdc+ 7][sj] = k1v.w;
            kT[sdc+ 8][sj] = k2v.x; kT[sdc+ 9][sj] = k2v.y; kT[sdc+10][sj] = k2v.z; kT[sdc+11][sj] = k2v.w;
            kT[sdc+12][sj] = k3v.x; kT[sdc+13][sj] = k3v.y; kT[sdc+14][sj] = k3v.z; kT[sdc+15][sj] = k3v.w;
            vT[sj][sdc+ 0] = v0v.x; vT[sj][sdc+ 1] = v0v.y; vT[sj][sdc+ 2] = v0v.z; vT[sj][sdc+ 3] = v0v.w;
            vT[sj][sdc+ 4] = v1v.x; vT[sj][sdc+ 5] = v1v.y; vT[sj][sdc+ 6] = v1v.z; vT[sj][sdc+ 7] = v1v.w;
            vT[sj][sdc+ 8] = v2v.x; vT[sj][sdc+ 9] = v2v.y; vT[sj][sdc+10] = v2v.z; vT[sj][sdc+11] = v2v.w;
            vT[sj][sdc+12] = v3v.x; vT[sj][sdc+13] = v3v.y; vT[sj][sdc+14] = v3v.z; vT[sj][sdc+15] = v3v.w;
        }
        __syncthreads();

        const int jg = j0 + lane;
        float s[8];
        #pragma unroll
        for (int r = 0; r < 8; r++)
            s[r] = rel[((size_t)h*S_ + (iw0 + r)) * J_ + jg];

        #pragma unroll 8
        for (int d = 0; d < 64; d++) {
            const float kval = kT[d][lane];
            const float4 qa = *(const float4*)&qT[d][wv*8];
            const float4 qb = *(const float4*)&qT[d][wv*8 + 4];
            s[0] += qa.x*kval; s[1] += qa.y*kval; s[2] += qa.z*kval; s[3] += qa.w*kval;
            s[4] += qb.x*kval; s[5] += qb.y*kval; s[6] += qb.z*kval; s[7] += qb.w*kval;
        }

        #pragma unroll
        for (int r = 0; r < 8; r++) {
            const int irow = iw0 + r;
            const float sv = (jg <= irow + XL_) ? s[r]*scale : -1e30f;
            float mx = sv;
            #pragma unroll
            for (int off = 32; off >= 1; off >>= 1)
                mx = fmaxf(mx, __shfl_xor(mx, off));
            const float m_new = fmaxf(m_r[r], mx);
            const float alpha = __expf(m_r[r] - m_new);
            const float p = __expf(sv - m_new);
            float ps = p;
            #pragma unroll
            for (int off = 32; off >= 1; off >>= 1)
                ps += __shfl_xor(ps, off);
            l_r[r] = l_r[r]*alpha + ps;
            acc[r] *= alpha;
            m_r[r] = m_new;
            pT[wv][lane][r] = p;
        }

        #pragma unroll 8
        for (int j = 0; j < 64; j++) {
            const float vval = vT[j][lane];
            const float4 pa = *(const float4*)&pT[wv][j][0];
            const float4 pb = *(const float4*)&pT[wv][j][4];
            acc[0] += pa.x*vval; acc[1] += pa.y*vval; acc[2] += pa.z*vval; acc[3] += pa.w*vval;
            acc[4] += pb.x*vval; acc[5] += pb.y*vval; acc[6] += pb.z*vval; acc[7] += pb.w*vval;
        }
        __syncthreads();
    }

    #pragma unroll
    for (int r = 0; r < 8; r++)
        o_ws[(size_t)(b*S_ + iw0 + r) * HD_ + h*D_ + lane] = acc[r] / l_r[r];
}

// ---------------------------------------------------------------------------
// kNN attention + gate merge. grid 4096 (= b*S+s), block 512: wave = head, lane = d.
// Streams the 512 MB knn tensor exactly once, fully coalesced (2 KB / instr).
// ---------------------------------------------------------------------------
__global__ __launch_bounds__(512) void knn_merge(
    const float* __restrict__ q_ws, const float* __restrict__ knn,
    const float* __restrict__ o_ws, const float* __restrict__ gate,
    float* __restrict__ merged)
{
    __shared__ float p_s[H_][KK_];
    const int t    = threadIdx.x;
    const int wv   = t >> 6;          // head
    const int lane = t & 63;
    const size_t bs = blockIdx.x;
    const float* base = knn + bs * (size_t)(KK_ * 2 * HD_);
    const float qv = q_ws[bs * HD_ + t];

    #pragma unroll 4
    for (int kk = 0; kk < KK_; kk++) {
        float pr = qv * base[(size_t)(kk*2) * HD_ + t];
        #pragma unroll
        for (int off = 32; off >= 1; off >>= 1)
            pr += __shfl_xor(pr, off);
        if (lane == 0) p_s[wv][kk] = pr;
    }
    __syncthreads();

    const float sval = p_s[wv][lane & 31] * 0.125f;
    float mx = sval;
    #pragma unroll
    for (int off = 16; off >= 1; off >>= 1)
        mx = fmaxf(mx, __shfl_xor(mx, off));
    const float e = __expf(sval - mx);
    float es = e;
    #pragma unroll
    for (int off = 16; off >= 1; off >>= 1)
        es += __shfl_xor(es, off);
    if (lane < 32) p_s[wv][lane] = e / es;
    __syncthreads();

    float acc = 0.f;
    #pragma unroll 4
    for (int kk = 0; kk < KK_; kk++)
        acc += p_s[wv][kk] * base[(size_t)(kk*2 + 1) * HD_ + t];

    const float g = 1.f / (1.f + __expf(-gate[wv]));
    const float o = o_ws[bs * HD_ + t];
    merged[bs * HD_ + t] = o * g + acc * (1.f - g);
}

// ---------------------------------------------------------------------------
extern "C" void kernel_launch(void* const* d_in, const int* in_sizes, int n_in,
                              void* d_out, int out_size, void* d_ws, size_t ws_size,
                              hipStream_t stream)
{
    (void)in_sizes; (void)n_in; (void)out_size; (void)ws_size;
    const float* x    = (const float*)d_in[0];
    const float* rel  = (const float*)d_in[1];
    const float* xlm  = (const float*)d_in[2];
    const float* knn  = (const float*)d_in[3];
    const float* Wq   = (const float*)d_in[4];
    const float* bq   = (const float*)d_in[5];
    const float* Wk   = (const float*)d_in[6];
    const float* bk   = (const float*)d_in[7];
    const float* Wv   = (const float*)d_in[8];
    const float* bv   = (const float*)d_in[9];
    const float* Wo   = (const float*)d_in[10];
    const float* bo   = (const float*)d_in[11];
    const float* gate = (const float*)d_in[12];

    float* out    = (float*)d_out;
    float* kv_out = out + OUT1;           // [B,S,2,HD] second output
    float* q_ws   = (float*)d_ws;         // [B,S,HD]
    float* o_ws   = q_ws + OUT1;          // [B,S,HD] local-attn out
    float* mg_ws  = o_ws + OUT1;          // [B,S,HD] merged

    dim3 gg(64, 8, 1);
    gemm_bt<<<gg, 256, 0, stream>>>(x, Wq, bq, q_ws, 0);
    gemm_bt<<<gg, 256, 0, stream>>>(x, Wk, bk, kv_out, 1);
    gemm_bt<<<gg, 256, 0, stream>>>(x, Wv, bv, kv_out, 2);
    attn_local<<<dim3(32, 8, 4), 256, 0, stream>>>(q_ws, xlm, kv_out, rel, o_ws);
    knn_merge<<<dim3(4096), 512, 0, stream>>>(q_ws, knn, o_ws, gate, mg_ws);
    gemm_bt<<<gg, 256, 0, stream>>>(mg_ws, Wo, bo, out, 0);
}